// Round 1
// baseline (105.412 us; speedup 1.0000x reference)
//
#include <hip/hip_runtime.h>

// ---------------------------------------------------------------------------
// SparseAttention v12: v11 (101.3us) with the two GEMM K-loops converted from
// single-buffered (STAGE -> syncthreads(vmcnt0) -> compute -> syncthreads) to
// the minimal 2-phase double-buffer (T3-min): 2x LDS halves (48KB, still
// 3 blocks/CU), ONE barrier per K-step, prefetch of tile t+1 issued right
// after the barrier so its 6 global_load_lds overlap the compute phase of
// tile t. vmcnt(0) wait lands a full compute-phase after issue. Matters most
// for gemm_out (grid=256 = 1 block/CU -> no cross-block latency hiding).
// prep (x->bf16, weight transposes) -> gemm_qkv (bf16, 64x128 tile, BK=64,
// 48KB LDS dbuf, 768 blocks = 3/CU) -> full-MFMA attention -> gemm_out
// (64x128, BK=64, dbuf, 256 blocks).
// B=2 S=2048 D=512 H=8 hd=64, fp32 I/O.
// Swizzle for 128-B rows (64 shorts): 16B-quad' = quad ^ (row&7) -> 2-way
// bank aliasing (free, m136). Fixed-overhead model: ~83us harness + kernels.
// Lessons held: no direct-fragment global loads (R6), no cooperative launch
// (R7), no in-loop fp32->bf16 on the ds_read->MFMA chain (R10).
// ---------------------------------------------------------------------------

typedef __bf16 bf16x8 __attribute__((ext_vector_type(8)));
typedef float  f32x4  __attribute__((ext_vector_type(4)));
typedef unsigned short u16;
typedef unsigned int   u32;

__device__ __forceinline__ u16 f2bf(float f) {
  u32 u = __builtin_bit_cast(u32, f);
  u += 0x7FFFu + ((u >> 16) & 1u);
  return (u16)(u >> 16);
}
__device__ __forceinline__ u32 pack2(u16 a, u16 b) {
  return (u32)a | ((u32)b << 16);
}
__device__ __forceinline__ void glds16(const void* g, void* l) {
  __builtin_amdgcn_global_load_lds(
      (const __attribute__((address_space(1))) void*)g,
      (__attribute__((address_space(3))) void*)l, 16, 0, 0);
}
__device__ __forceinline__ f32x4 mfma16(bf16x8 a, bf16x8 b, f32x4 c) {
  return __builtin_amdgcn_mfma_f32_16x16x32_bf16(a, b, c, 0, 0, 0);
}
// waitcnt(vmcnt=0) fused with s_barrier: all waves' global_load_lds for the
// current tile are LDS-visible before any wave proceeds. "memory" clobber
// pins all LDS reads/writes and glds issues to their program-order side.
#define VM0_BARRIER() asm volatile("s_waitcnt vmcnt(0)\n\ts_barrier" ::: "memory")

// ---------------------------------------------------------------------------
// prep: blocks [0,2048): round x to bf16 (float4/thread). [2048,2816):
// transpose+round w_qkv. [2816,3072): transpose+round w_out.
// ---------------------------------------------------------------------------
__global__ __launch_bounds__(256) void prep(
    const float4* __restrict__ X, uint2* __restrict__ XH,
    const float* __restrict__ Wq, u16* __restrict__ Wqt,
    const float* __restrict__ Wo, u16* __restrict__ Wot) {
  __shared__ float T[32][33];
  const int blk = blockIdx.x, t = threadIdx.x;
  if (blk < 2048) {
    int i = blk * 256 + t;
    float4 v = X[i];
    XH[i] = make_uint2(pack2(f2bf(v.x), f2bf(v.y)), pack2(f2bf(v.z), f2bf(v.w)));
    return;
  }
  const float* W;
  u16* Wt;
  int n0, k0, N;
  if (blk < 2816) {
    int idx = blk - 2048;
    W = Wq; Wt = Wqt; N = 1536;
    n0 = (idx % 48) * 32; k0 = (idx / 48) * 32;
  } else {
    int idx = blk - 2816;
    W = Wo; Wt = Wot; N = 512;
    n0 = (idx % 16) * 32; k0 = (idx / 16) * 32;
  }
  const int r = t >> 3, c = (t & 7) * 4;
  float4 v = *(const float4*)&W[(size_t)(k0 + r) * N + n0 + c];
  T[c][r] = v.x; T[c + 1][r] = v.y; T[c + 2][r] = v.z; T[c + 3][r] = v.w;
  __syncthreads();
  u16 a = f2bf(T[r][c]),      b = f2bf(T[r][c + 1]);
  u16 cc = f2bf(T[r][c + 2]), d = f2bf(T[r][c + 3]);
  *(uint2*)&Wt[(size_t)(n0 + r) * 512 + k0 + c] =
      make_uint2(pack2(a, b), pack2(cc, d));
}

// ---------------------------------------------------------------------------
// gemm_qkv: bf16(x) [4096,512] @ wqt[1536][512]^T + bias -> Q*0.125/K/V bf16.
// 64x128 tile, BK=64 (8 iters), double-buffered. 4 waves 2x2, wave 32x64,
// 16 MFMA/wave/iter, 48 KB LDS. grid (12,64) = 768 blocks = 3/CU.
// LDS rows are 64 shorts (128 B); swizzle: quad' = quad ^ (row&7).
// ---------------------------------------------------------------------------
__global__ __launch_bounds__(256) void gemm_qkv(
    const u16* __restrict__ Ah, const u16* __restrict__ Bt,
    const float* __restrict__ bias,
    u16* __restrict__ Qb, u16* __restrict__ Kb, u16* __restrict__ Vb) {
  __shared__ __align__(16) u16 sA[2][64 * 64];    // 16 KB
  __shared__ __align__(16) u16 sB[2][128 * 64];   // 32 KB

  const int t = threadIdx.x, l = t & 63, w = t >> 6;
  const int wm = w >> 1, wn = w & 1;
  const int mBase = blockIdx.y * 64, nBase = blockIdx.x * 128;

  // staging: one glds = 8 rows x 8 quads. lane l -> row l>>3, LDS quad l&7,
  // global quad (l&7) ^ ((l>>3)&7).
  const int rsub = l >> 3;
  const int qsrc = (l & 7) ^ (rsub & 7);
  const u16* gA0 = Ah + (size_t)(mBase + w * 16 + rsub) * 512 + qsrc * 8;
  const u16* gA1 = Ah + (size_t)(mBase + w * 16 + 8 + rsub) * 512 + qsrc * 8;
  const int oA0 = (w * 16) * 64;
  const int oA1 = (w * 16 + 8) * 64;
  const u16* gB[4];
  int oB[4];
#pragma unroll
  for (int j = 0; j < 4; ++j) {
    gB[j] = Bt + (size_t)(nBase + w * 32 + j * 8 + rsub) * 512 + qsrc * 8;
    oB[j] = (w * 32 + j * 8) * 64;
  }

  // fragment offsets: row*64 + ((s*4+kg) ^ (row&7))*8, s = k-step 0/1
  const int r15 = l & 15, kg = l >> 4;
  const int sw = r15 & 7;
  int aoff[2][2], boff[4][2];
#pragma unroll
  for (int mt = 0; mt < 2; ++mt)
#pragma unroll
    for (int s = 0; s < 2; ++s)
      aoff[mt][s] = (wm * 32 + mt * 16 + r15) * 64 + (((s * 4 + kg) ^ sw) * 8);
#pragma unroll
  for (int nt = 0; nt < 4; ++nt)
#pragma unroll
    for (int s = 0; s < 2; ++s)
      boff[nt][s] = (wn * 64 + nt * 16 + r15) * 64 + (((s * 4 + kg) ^ sw) * 8);

  f32x4 acc[2][4];
#pragma unroll
  for (int i = 0; i < 2; ++i)
#pragma unroll
    for (int j = 0; j < 4; ++j) acc[i][j] = (f32x4){0.f, 0.f, 0.f, 0.f};

  auto stage = [&](int h, int k0) {
    glds16(gA0 + k0, sA[h] + oA0);
    glds16(gA1 + k0, sA[h] + oA1);
#pragma unroll
    for (int j = 0; j < 4; ++j) glds16(gB[j] + k0, sB[h] + oB[j]);
  };

  stage(0, 0);  // prologue: tile 0 -> half 0
#pragma unroll
  for (int it = 0; it < 8; ++it) {
    VM0_BARRIER();                       // tile `it` resident in half it&1
    if (it < 7) stage((it + 1) & 1, (it + 1) * 64);  // overlaps compute below
    const u16* sAh = sA[it & 1];
    const u16* sBh = sB[it & 1];
#pragma unroll
    for (int s = 0; s < 2; ++s) {
      bf16x8 b[4];
#pragma unroll
      for (int nt = 0; nt < 4; ++nt) b[nt] = *(const bf16x8*)(sBh + boff[nt][s]);
      bf16x8 a0 = *(const bf16x8*)(sAh + aoff[0][s]);
      bf16x8 a1 = *(const bf16x8*)(sAh + aoff[1][s]);
#pragma unroll
      for (int nt = 0; nt < 4; ++nt) {
        acc[0][nt] = mfma16(a0, b[nt], acc[0][nt]);
        acc[1][nt] = mfma16(a1, b[nt], acc[1][nt]);
      }
    }
  }

  const int lq = l >> 4;
  const int seg = nBase >> 9, colb = nBase & 511;
#pragma unroll
  for (int mt = 0; mt < 2; ++mt) {
    int row0 = mBase + wm * 32 + mt * 16 + lq * 4;
#pragma unroll
    for (int nt = 0; nt < 4; ++nt) {
      int col = wn * 64 + nt * 16 + r15;
      float bv = bias[nBase + col];
      int cc = colb + col;
      if (seg == 0) {
#pragma unroll
        for (int r = 0; r < 4; ++r)
          Qb[(size_t)(row0 + r) * 512 + cc] = f2bf((acc[mt][nt][r] + bv) * 0.125f);
      } else if (seg == 1) {
#pragma unroll
        for (int r = 0; r < 4; ++r)
          Kb[(size_t)(row0 + r) * 512 + cc] = f2bf(acc[mt][nt][r] + bv);
      } else {
#pragma unroll
        for (int r = 0; r < 4; ++r)
          Vb[(size_t)(row0 + r) * 512 + cc] = f2bf(acc[mt][nt][r] + bv);
      }
    }
  }
}

// ---------------------------------------------------------------------------
// attn_mfma: per (64-row tile, h, b). QK^T and PV on matrix cores.
// Writes attention output as bf16 (single-product out-GEMM downstream).
// ---------------------------------------------------------------------------
__global__ __launch_bounds__(256) void attn_mfma(
    const u16* __restrict__ Qb, const u16* __restrict__ Kb,
    const u16* __restrict__ Vb, u16* __restrict__ Oh) {
  const int tile = blockIdx.x, h = blockIdx.y, b = blockIdx.z;
  const int base = tile * 64;
  const size_t hb = (size_t)b * 2048;

  __shared__ __align__(16) u16 Qs[64][72];    // [s][d]
  __shared__ __align__(16) u16 Ks[128][72];   // [j][d]
  __shared__ __align__(16) u16 Vt[64][136];   // [d][j]
  __shared__ __align__(16) u16 Pp[64][136];   // [s][j]

  const int t = threadIdx.x, l = t & 63, w = t >> 6;
  const int r15 = l & 15, kg = l >> 4;

  // stage Q
  {
    int r = t >> 2, c0 = (t & 3) * 16;
    const uint4* src = (const uint4*)&Qb[(hb + base + r) * 512 + h * 64 + c0];
    *(uint4*)&Qs[r][c0] = src[0];
    *(uint4*)&Qs[r][c0 + 8] = src[1];
  }
  // stage K (clamped band)
  {
    int j = t >> 1, half = (t & 1) * 32;
    int ja = min(max(base - 32 + j, 0), 2047);
    const uint4* src = (const uint4*)&Kb[(hb + ja) * 512 + h * 64 + half];
    uint4* dst = (uint4*)&Ks[j][half];
    dst[0] = src[0]; dst[1] = src[1]; dst[2] = src[2]; dst[3] = src[3];
  }
  // stage V transposed
  {
    int j = t >> 1, ds = (t & 1) * 32;
    int ja = min(max(base - 32 + j, 0), 2047);
    const u16* src = &Vb[(hb + ja) * 512 + h * 64 + ds];
    u16 tmp[32];
    *(uint4*)&tmp[0]  = *(const uint4*)(src);
    *(uint4*)&tmp[8]  = *(const uint4*)(src + 8);
    *(uint4*)&tmp[16] = *(const uint4*)(src + 16);
    *(uint4*)&tmp[24] = *(const uint4*)(src + 24);
#pragma unroll
    for (int i = 0; i < 32; ++i) Vt[ds + i][j] = tmp[i];
  }
  __syncthreads();

  // QK^T: wave w owns rows [w*16, w*16+16)
  bf16x8 aQ0 = *(const bf16x8*)&Qs[w * 16 + r15][kg * 8];
  bf16x8 aQ1 = *(const bf16x8*)&Qs[w * 16 + r15][32 + kg * 8];
  f32x4 zero = (f32x4){0.f, 0.f, 0.f, 0.f};
  f32x4 sacc[8];
#pragma unroll
  for (int nt = 0; nt < 8; ++nt) {
    bf16x8 b0 = *(const bf16x8*)&Ks[nt * 16 + r15][kg * 8];
    bf16x8 b1 = *(const bf16x8*)&Ks[nt * 16 + r15][32 + kg * 8];
    sacc[nt] = mfma16(aQ0, b0, zero);
    sacc[nt] = mfma16(aQ1, b1, sacc[nt]);
  }

  // mask + softmax (C-layout: row = w*16+kg*4+r, col = nt*16+r15)
#pragma unroll
  for (int r = 0; r < 4; ++r) {
    int s_abs = base + w * 16 + kg * 4 + r;
    float m = -3.0e38f;
#pragma unroll
    for (int nt = 0; nt < 8; ++nt) {
      int j_abs = base - 32 + nt * 16 + r15;
      int dlt = j_abs - s_abs;
      bool valid = (dlt >= -32) && (dlt <= 32) && (j_abs >= 0) && (j_abs < 2048);
      float v = valid ? sacc[nt][r] : -1.0e9f;
      sacc[nt][r] = v;
      m = fmaxf(m, v);
    }
#pragma unroll
    for (int msk = 1; msk < 16; msk <<= 1) m = fmaxf(m, __shfl_xor(m, msk, 64));
    float s_ = 0.f;
#pragma unroll
    for (int nt = 0; nt < 8; ++nt) {
      float e = __expf(sacc[nt][r] - m);
      sacc[nt][r] = e;
      s_ += e;
    }
#pragma unroll
    for (int msk = 1; msk < 16; msk <<= 1) s_ += __shfl_xor(s_, msk, 64);
    float inv = 1.0f / s_;
#pragma unroll
    for (int nt = 0; nt < 8; ++nt)
      Pp[w * 16 + kg * 4 + r][nt * 16 + r15] = f2bf(sacc[nt][r] * inv);
  }
  __syncthreads();

  // PV
  bf16x8 aP[4];
#pragma unroll
  for (int kt = 0; kt < 4; ++kt)
    aP[kt] = *(const bf16x8*)&Pp[w * 16 + r15][kt * 32 + kg * 8];
  f32x4 oacc[4];
#pragma unroll
  for (int nt = 0; nt < 4; ++nt) oacc[nt] = zero;
#pragma unroll
  for (int nt = 0; nt < 4; ++nt) {
#pragma unroll
    for (int kt = 0; kt < 4; ++kt) {
      bf16x8 bV = *(const bf16x8*)&Vt[nt * 16 + r15][kt * 32 + kg * 8];
      oacc[nt] = mfma16(aP[kt], bV, oacc[nt]);
    }
  }

  // epilogue: write O as bf16
#pragma unroll
  for (int nt = 0; nt < 4; ++nt) {
#pragma unroll
    for (int r = 0; r < 4; ++r) {
      size_t idx =
          (hb + base + w * 16 + kg * 4 + r) * 512 + h * 64 + nt * 16 + r15;
      Oh[idx] = f2bf(oacc[nt][r]);
    }
  }
}

// ---------------------------------------------------------------------------
// gemm_out: [4096,512](bf16) @ [512,512]^T(bf16) + bias -> fp32 out.
// 64x128 tile, BK=64 (8 iters), double-buffered 48 KB LDS, grid (4,64) =
// 256 blocks = 1/CU (no cross-block overlap -> dbuf matters most here).
// ---------------------------------------------------------------------------
__global__ __launch_bounds__(256) void gemm_out(
    const u16* __restrict__ Ah, const u16* __restrict__ Bt,
    const float* __restrict__ bias, float* __restrict__ Cf) {
  __shared__ __align__(16) u16 sA[2][64 * 64];
  __shared__ __align__(16) u16 sB[2][128 * 64];

  const int t = threadIdx.x, l = t & 63, w = t >> 6;
  const int wm = w >> 1, wn = w & 1;
  const int mBase = blockIdx.y * 64, nBase = blockIdx.x * 128;

  const int rsub = l >> 3;
  const int qsrc = (l & 7) ^ (rsub & 7);
  const u16* gA0 = Ah + (size_t)(mBase + w * 16 + rsub) * 512 + qsrc * 8;
  const u16* gA1 = Ah + (size_t)(mBase + w * 16 + 8 + rsub) * 512 + qsrc * 8;
  const int oA0 = (w * 16) * 64;
  const int oA1 = (w * 16 + 8) * 64;
  const u16* gB[4];
  int oB[4];
#pragma unroll
  for (int j = 0; j < 4; ++j) {
    gB[j] = Bt + (size_t)(nBase + w * 32 + j * 8 + rsub) * 512 + qsrc * 8;
    oB[j] = (w * 32 + j * 8) * 64;
  }

  const int r15 = l & 15, kg = l >> 4;
  const int sw = r15 & 7;
  int aoff[2][2], boff[4][2];
#pragma unroll
  for (int mt = 0; mt < 2; ++mt)
#pragma unroll
    for (int s = 0; s < 2; ++s)
      aoff[mt][s] = (wm * 32 + mt * 16 + r15) * 64 + (((s * 4 + kg) ^ sw) * 8);
#pragma unroll
  for (int nt = 0; nt < 4; ++nt)
#pragma unroll
    for (int s = 0; s < 2; ++s)
      boff[nt][s] = (wn * 64 + nt * 16 + r15) * 64 + (((s * 4 + kg) ^ sw) * 8);

  f32x4 acc[2][4];
#pragma unroll
  for (int i = 0; i < 2; ++i)
#pragma unroll
    for (int j = 0; j < 4; ++j) acc[i][j] = (f32x4){0.f, 0.f, 0.f, 0.f};

  auto stage = [&](int h, int k0) {
    glds16(gA0 + k0, sA[h] + oA0);
    glds16(gA1 + k0, sA[h] + oA1);
#pragma unroll
    for (int j = 0; j < 4; ++j) glds16(gB[j] + k0, sB[h] + oB[j]);
  };

  stage(0, 0);
#pragma unroll
  for (int it = 0; it < 8; ++it) {
    VM0_BARRIER();
    if (it < 7) stage((it + 1) & 1, (it + 1) * 64);
    const u16* sAh = sA[it & 1];
    const u16* sBh = sB[it & 1];
#pragma unroll
    for (int s = 0; s < 2; ++s) {
      bf16x8 b[4];
#pragma unroll
      for (int nt = 0; nt < 4; ++nt) b[nt] = *(const bf16x8*)(sBh + boff[nt][s]);
      bf16x8 a0 = *(const bf16x8*)(sAh + aoff[0][s]);
      bf16x8 a1 = *(const bf16x8*)(sAh + aoff[1][s]);
#pragma unroll
      for (int nt = 0; nt < 4; ++nt) {
        acc[0][nt] = mfma16(a0, b[nt], acc[0][nt]);
        acc[1][nt] = mfma16(a1, b[nt], acc[1][nt]);
      }
    }
  }

  const int lq = l >> 4;
#pragma unroll
  for (int mt = 0; mt < 2; ++mt) {
    int row0 = mBase + wm * 32 + mt * 16 + lq * 4;
#pragma unroll
    for (int nt = 0; nt < 4; ++nt) {
      int col = nBase + wn * 64 + nt * 16 + r15;
      float bv = bias[col];
#pragma unroll
      for (int r = 0; r < 4; ++r)
        Cf[(size_t)(row0 + r) * 512 + col] = acc[mt][nt][r] + bv;
    }
  }
}

// ---------------------------------------------------------------------------
extern "C" void kernel_launch(void* const* d_in, const int* in_sizes, int n_in,
                              void* d_out, int out_size, void* d_ws, size_t ws_size,
                              hipStream_t stream) {
  const float* x     = (const float*)d_in[0];
  const float* w_qkv = (const float*)d_in[1];
  const float* b_qkv = (const float*)d_in[2];
  const float* w_out = (const float*)d_in[3];
  const float* b_out = (const float*)d_in[4];
  float* out = (float*)d_out;

  // workspace layout (~22.6 MB)
  char* ws = (char*)d_ws;
  u16* xh  = (u16*)(ws + 0);          // 4096x512 bf16 = 4194304
  u16* wqt = (u16*)(ws + 4194304);    // 1536x512 bf16 = 1572864
  u16* wot = (u16*)(ws + 5767168);    // 512x512 bf16  = 524288
  u16* qb  = (u16*)(ws + 6291456);    // 4096x512 bf16 (pre-scaled) = 4194304
  u16* kb  = (u16*)(ws + 10485760);   // 4194304
  u16* vb  = (u16*)(ws + 14680064);   // 4194304
  u16* aoh = (u16*)(ws + 18874368);   // 4194304

  prep<<<3072, 256, 0, stream>>>((const float4*)x, (uint2*)xh,
                                 w_qkv, wqt, w_out, wot);
  gemm_qkv<<<dim3(12, 64), 256, 0, stream>>>(xh, wqt, b_qkv, qb, kb, vb);
  attn_mfma<<<dim3(32, 8, 2), 256, 0, stream>>>(qb, kb, vb, aoh);
  gemm_out<<<dim3(4, 64), 256, 0, stream>>>(aoh, wot, b_out, out);
}

// Round 3
// 101.961 us; speedup vs baseline: 1.0338x; 1.0338x over previous
//
#include <hip/hip_runtime.h>

// ---------------------------------------------------------------------------
// SparseAttention v13 = v11 restored (verified best: 100.4us / 101.3us).
// R2: resubmission — R2 bench failed on container acquisition (infra), not
// kernel. R1 post-mortem: explicit 2-phase LDS double-buffer (v12) regressed
// to 105.4us — per-wave vmcnt(0) drain stayed on the critical path (prefetch
// only got ~1 compute-phase of cover) while adding prologue + tail-branch
// overhead; cross-block overlap at 3 blocks/CU already hid staging latency
// (guide §5 m99/m100 lesson confirmed on this workload).
// prep (x->bf16, weight transposes) -> gemm_qkv (bf16 single-product, 64x128
// tile, BK=64, 24KB LDS, 768 blocks = 3/CU) -> full-MFMA attention ->
// single-product out GEMM (64x128, BK=64, 256 blocks).
// B=2 S=2048 D=512 H=8 hd=64, fp32 I/O.
// Swizzle for 128-B rows (64 shorts): 16B-quad' = quad ^ (row&7) -> 2-way
// bank aliasing (free, m136). Fixed-overhead model: ~83us harness + kernels.
// Lessons held: no direct-fragment global loads (R6), no cooperative launch
// (R7), no in-loop fp32->bf16 on the ds_read->MFMA chain (R10), no explicit
// LDS double-buffer (R12/v12).
// ---------------------------------------------------------------------------

typedef __bf16 bf16x8 __attribute__((ext_vector_type(8)));
typedef float  f32x4  __attribute__((ext_vector_type(4)));
typedef unsigned short u16;
typedef unsigned int   u32;

__device__ __forceinline__ u16 f2bf(float f) {
  u32 u = __builtin_bit_cast(u32, f);
  u += 0x7FFFu + ((u >> 16) & 1u);
  return (u16)(u >> 16);
}
__device__ __forceinline__ u32 pack2(u16 a, u16 b) {
  return (u32)a | ((u32)b << 16);
}
__device__ __forceinline__ void glds16(const void* g, void* l) {
  __builtin_amdgcn_global_load_lds(
      (const __attribute__((address_space(1))) void*)g,
      (__attribute__((address_space(3))) void*)l, 16, 0, 0);
}
__device__ __forceinline__ f32x4 mfma16(bf16x8 a, bf16x8 b, f32x4 c) {
  return __builtin_amdgcn_mfma_f32_16x16x32_bf16(a, b, c, 0, 0, 0);
}

// ---------------------------------------------------------------------------
// prep: blocks [0,2048): round x to bf16 (float4/thread). [2048,2816):
// transpose+round w_qkv. [2816,3072): transpose+round w_out.
// ---------------------------------------------------------------------------
__global__ __launch_bounds__(256) void prep(
    const float4* __restrict__ X, uint2* __restrict__ XH,
    const float* __restrict__ Wq, u16* __restrict__ Wqt,
    const float* __restrict__ Wo, u16* __restrict__ Wot) {
  __shared__ float T[32][33];
  const int blk = blockIdx.x, t = threadIdx.x;
  if (blk < 2048) {
    int i = blk * 256 + t;
    float4 v = X[i];
    XH[i] = make_uint2(pack2(f2bf(v.x), f2bf(v.y)), pack2(f2bf(v.z), f2bf(v.w)));
    return;
  }
  const float* W;
  u16* Wt;
  int n0, k0, N;
  if (blk < 2816) {
    int idx = blk - 2048;
    W = Wq; Wt = Wqt; N = 1536;
    n0 = (idx % 48) * 32; k0 = (idx / 48) * 32;
  } else {
    int idx = blk - 2816;
    W = Wo; Wt = Wot; N = 512;
    n0 = (idx % 16) * 32; k0 = (idx / 16) * 32;
  }
  const int r = t >> 3, c = (t & 7) * 4;
  float4 v = *(const float4*)&W[(size_t)(k0 + r) * N + n0 + c];
  T[c][r] = v.x; T[c + 1][r] = v.y; T[c + 2][r] = v.z; T[c + 3][r] = v.w;
  __syncthreads();
  u16 a = f2bf(T[r][c]),      b = f2bf(T[r][c + 1]);
  u16 cc = f2bf(T[r][c + 2]), d = f2bf(T[r][c + 3]);
  *(uint2*)&Wt[(size_t)(n0 + r) * 512 + k0 + c] =
      make_uint2(pack2(a, b), pack2(cc, d));
}

// ---------------------------------------------------------------------------
// gemm_qkv: bf16(x) [4096,512] @ wqt[1536][512]^T + bias -> Q*0.125/K/V bf16.
// 64x128 tile, BK=64 (8 iters), single product. 4 waves 2x2, wave 32x64,
// 16 MFMA/wave/iter, 24 KB LDS. grid (12,64) = 768 blocks = 3/CU.
// LDS rows are 64 shorts (128 B); swizzle: quad' = quad ^ (row&7).
// ---------------------------------------------------------------------------
__global__ __launch_bounds__(256) void gemm_qkv(
    const u16* __restrict__ Ah, const u16* __restrict__ Bt,
    const float* __restrict__ bias,
    u16* __restrict__ Qb, u16* __restrict__ Kb, u16* __restrict__ Vb) {
  __shared__ __align__(16) u16 sA[64 * 64];    // 8 KB
  __shared__ __align__(16) u16 sB[128 * 64];   // 16 KB

  const int t = threadIdx.x, l = t & 63, w = t >> 6;
  const int wm = w >> 1, wn = w & 1;
  const int mBase = blockIdx.y * 64, nBase = blockIdx.x * 128;

  // staging: one glds = 8 rows x 8 quads. lane l -> row l>>3, LDS quad l&7,
  // global quad (l&7) ^ ((l>>3)&7).
  const int rsub = l >> 3;
  const int qsrc = (l & 7) ^ (rsub & 7);
  const u16* gA0 = Ah + (size_t)(mBase + w * 16 + rsub) * 512 + qsrc * 8;
  const u16* gA1 = Ah + (size_t)(mBase + w * 16 + 8 + rsub) * 512 + qsrc * 8;
  u16* lA0 = sA + (w * 16) * 64;
  u16* lA1 = sA + (w * 16 + 8) * 64;
  const u16* gB[4];
  u16* lB[4];
#pragma unroll
  for (int j = 0; j < 4; ++j) {
    gB[j] = Bt + (size_t)(nBase + w * 32 + j * 8 + rsub) * 512 + qsrc * 8;
    lB[j] = sB + (w * 32 + j * 8) * 64;
  }

  // fragment offsets: row*64 + ((s*4+kg) ^ (row&7))*8, s = k-step 0/1
  const int r15 = l & 15, kg = l >> 4;
  const int sw = r15 & 7;
  int aoff[2][2], boff[4][2];
#pragma unroll
  for (int mt = 0; mt < 2; ++mt)
#pragma unroll
    for (int s = 0; s < 2; ++s)
      aoff[mt][s] = (wm * 32 + mt * 16 + r15) * 64 + (((s * 4 + kg) ^ sw) * 8);
#pragma unroll
  for (int nt = 0; nt < 4; ++nt)
#pragma unroll
    for (int s = 0; s < 2; ++s)
      boff[nt][s] = (wn * 64 + nt * 16 + r15) * 64 + (((s * 4 + kg) ^ sw) * 8);

  f32x4 acc[2][4];
#pragma unroll
  for (int i = 0; i < 2; ++i)
#pragma unroll
    for (int j = 0; j < 4; ++j) acc[i][j] = (f32x4){0.f, 0.f, 0.f, 0.f};

  for (int k0 = 0; k0 < 512; k0 += 64) {
    glds16(gA0 + k0, lA0);
    glds16(gA1 + k0, lA1);
#pragma unroll
    for (int j = 0; j < 4; ++j) glds16(gB[j] + k0, lB[j]);
    __syncthreads();
#pragma unroll
    for (int s = 0; s < 2; ++s) {
      bf16x8 b[4];
#pragma unroll
      for (int nt = 0; nt < 4; ++nt) b[nt] = *(const bf16x8*)(sB + boff[nt][s]);
      bf16x8 a0 = *(const bf16x8*)(sA + aoff[0][s]);
      bf16x8 a1 = *(const bf16x8*)(sA + aoff[1][s]);
#pragma unroll
      for (int nt = 0; nt < 4; ++nt) {
        acc[0][nt] = mfma16(a0, b[nt], acc[0][nt]);
        acc[1][nt] = mfma16(a1, b[nt], acc[1][nt]);
      }
    }
    __syncthreads();
  }

  const int lq = l >> 4;
  const int seg = nBase >> 9, colb = nBase & 511;
#pragma unroll
  for (int mt = 0; mt < 2; ++mt) {
    int row0 = mBase + wm * 32 + mt * 16 + lq * 4;
#pragma unroll
    for (int nt = 0; nt < 4; ++nt) {
      int col = wn * 64 + nt * 16 + r15;
      float bv = bias[nBase + col];
      int cc = colb + col;
      if (seg == 0) {
#pragma unroll
        for (int r = 0; r < 4; ++r)
          Qb[(size_t)(row0 + r) * 512 + cc] = f2bf((acc[mt][nt][r] + bv) * 0.125f);
      } else if (seg == 1) {
#pragma unroll
        for (int r = 0; r < 4; ++r)
          Kb[(size_t)(row0 + r) * 512 + cc] = f2bf(acc[mt][nt][r] + bv);
      } else {
#pragma unroll
        for (int r = 0; r < 4; ++r)
          Vb[(size_t)(row0 + r) * 512 + cc] = f2bf(acc[mt][nt][r] + bv);
      }
    }
  }
}

// ---------------------------------------------------------------------------
// attn_mfma: per (64-row tile, h, b). QK^T and PV on matrix cores.
// Writes attention output as bf16 (single-product out-GEMM downstream).
// ---------------------------------------------------------------------------
__global__ __launch_bounds__(256) void attn_mfma(
    const u16* __restrict__ Qb, const u16* __restrict__ Kb,
    const u16* __restrict__ Vb, u16* __restrict__ Oh) {
  const int tile = blockIdx.x, h = blockIdx.y, b = blockIdx.z;
  const int base = tile * 64;
  const size_t hb = (size_t)b * 2048;

  __shared__ __align__(16) u16 Qs[64][72];    // [s][d]
  __shared__ __align__(16) u16 Ks[128][72];   // [j][d]
  __shared__ __align__(16) u16 Vt[64][136];   // [d][j]
  __shared__ __align__(16) u16 Pp[64][136];   // [s][j]

  const int t = threadIdx.x, l = t & 63, w = t >> 6;
  const int r15 = l & 15, kg = l >> 4;

  // stage Q
  {
    int r = t >> 2, c0 = (t & 3) * 16;
    const uint4* src = (const uint4*)&Qb[(hb + base + r) * 512 + h * 64 + c0];
    *(uint4*)&Qs[r][c0] = src[0];
    *(uint4*)&Qs[r][c0 + 8] = src[1];
  }
  // stage K (clamped band)
  {
    int j = t >> 1, half = (t & 1) * 32;
    int ja = min(max(base - 32 + j, 0), 2047);
    const uint4* src = (const uint4*)&Kb[(hb + ja) * 512 + h * 64 + half];
    uint4* dst = (uint4*)&Ks[j][half];
    dst[0] = src[0]; dst[1] = src[1]; dst[2] = src[2]; dst[3] = src[3];
  }
  // stage V transposed
  {
    int j = t >> 1, ds = (t & 1) * 32;
    int ja = min(max(base - 32 + j, 0), 2047);
    const u16* src = &Vb[(hb + ja) * 512 + h * 64 + ds];
    u16 tmp[32];
    *(uint4*)&tmp[0]  = *(const uint4*)(src);
    *(uint4*)&tmp[8]  = *(const uint4*)(src + 8);
    *(uint4*)&tmp[16] = *(const uint4*)(src + 16);
    *(uint4*)&tmp[24] = *(const uint4*)(src + 24);
#pragma unroll
    for (int i = 0; i < 32; ++i) Vt[ds + i][j] = tmp[i];
  }
  __syncthreads();

  // QK^T: wave w owns rows [w*16, w*16+16)
  bf16x8 aQ0 = *(const bf16x8*)&Qs[w * 16 + r15][kg * 8];
  bf16x8 aQ1 = *(const bf16x8*)&Qs[w * 16 + r15][32 + kg * 8];
  f32x4 zero = (f32x4){0.f, 0.f, 0.f, 0.f};
  f32x4 sacc[8];
#pragma unroll
  for (int nt = 0; nt < 8; ++nt) {
    bf16x8 b0 = *(const bf16x8*)&Ks[nt * 16 + r15][kg * 8];
    bf16x8 b1 = *(const bf16x8*)&Ks[nt * 16 + r15][32 + kg * 8];
    sacc[nt] = mfma16(aQ0, b0, zero);
    sacc[nt] = mfma16(aQ1, b1, sacc[nt]);
  }

  // mask + softmax (C-layout: row = w*16+kg*4+r, col = nt*16+r15)
#pragma unroll
  for (int r = 0; r < 4; ++r) {
    int s_abs = base + w * 16 + kg * 4 + r;
    float m = -3.0e38f;
#pragma unroll
    for (int nt = 0; nt < 8; ++nt) {
      int j_abs = base - 32 + nt * 16 + r15;
      int dlt = j_abs - s_abs;
      bool valid = (dlt >= -32) && (dlt <= 32) && (j_abs >= 0) && (j_abs < 2048);
      float v = valid ? sacc[nt][r] : -1.0e9f;
      sacc[nt][r] = v;
      m = fmaxf(m, v);
    }
#pragma unroll
    for (int msk = 1; msk < 16; msk <<= 1) m = fmaxf(m, __shfl_xor(m, msk, 64));
    float s_ = 0.f;
#pragma unroll
    for (int nt = 0; nt < 8; ++nt) {
      float e = __expf(sacc[nt][r] - m);
      sacc[nt][r] = e;
      s_ += e;
    }
#pragma unroll
    for (int msk = 1; msk < 16; msk <<= 1) s_ += __shfl_xor(s_, msk, 64);
    float inv = 1.0f / s_;
#pragma unroll
    for (int nt = 0; nt < 8; ++nt)
      Pp[w * 16 + kg * 4 + r][nt * 16 + r15] = f2bf(sacc[nt][r] * inv);
  }
  __syncthreads();

  // PV
  bf16x8 aP[4];
#pragma unroll
  for (int kt = 0; kt < 4; ++kt)
    aP[kt] = *(const bf16x8*)&Pp[w * 16 + r15][kt * 32 + kg * 8];
  f32x4 oacc[4];
#pragma unroll
  for (int nt = 0; nt < 4; ++nt) oacc[nt] = zero;
#pragma unroll
  for (int nt = 0; nt < 4; ++nt) {
#pragma unroll
    for (int kt = 0; kt < 4; ++kt) {
      bf16x8 bV = *(const bf16x8*)&Vt[nt * 16 + r15][kt * 32 + kg * 8];
      oacc[nt] = mfma16(aP[kt], bV, oacc[nt]);
    }
  }

  // epilogue: write O as bf16
#pragma unroll
  for (int nt = 0; nt < 4; ++nt) {
#pragma unroll
    for (int r = 0; r < 4; ++r) {
      size_t idx =
          (hb + base + w * 16 + kg * 4 + r) * 512 + h * 64 + nt * 16 + r15;
      Oh[idx] = f2bf(oacc[nt][r]);
    }
  }
}

// ---------------------------------------------------------------------------
// gemm_out: [4096,512](bf16) @ [512,512]^T(bf16) + bias -> fp32 out.
// Single-product. 64x128 tile, BK=64 (8 iters), 24 KB LDS, grid (4,64).
// ---------------------------------------------------------------------------
__global__ __launch_bounds__(256) void gemm_out(
    const u16* __restrict__ Ah, const u16* __restrict__ Bt,
    const float* __restrict__ bias, float* __restrict__ Cf) {
  __shared__ __align__(16) u16 sA[64 * 64];
  __shared__ __align__(16) u16 sB[128 * 64];

  const int t = threadIdx.x, l = t & 63, w = t >> 6;
  const int wm = w >> 1, wn = w & 1;
  const int mBase = blockIdx.y * 64, nBase = blockIdx.x * 128;

  const int rsub = l >> 3;
  const int qsrc = (l & 7) ^ (rsub & 7);
  const u16* gA0 = Ah + (size_t)(mBase + w * 16 + rsub) * 512 + qsrc * 8;
  const u16* gA1 = Ah + (size_t)(mBase + w * 16 + 8 + rsub) * 512 + qsrc * 8;
  u16* lA0 = sA + (w * 16) * 64;
  u16* lA1 = sA + (w * 16 + 8) * 64;
  const u16* gB[4];
  u16* lB[4];
#pragma unroll
  for (int j = 0; j < 4; ++j) {
    gB[j] = Bt + (size_t)(nBase + w * 32 + j * 8 + rsub) * 512 + qsrc * 8;
    lB[j] = sB + (w * 32 + j * 8) * 64;
  }

  const int r15 = l & 15, kg = l >> 4;
  const int sw = r15 & 7;
  int aoff[2][2], boff[4][2];
#pragma unroll
  for (int mt = 0; mt < 2; ++mt)
#pragma unroll
    for (int s = 0; s < 2; ++s)
      aoff[mt][s] = (wm * 32 + mt * 16 + r15) * 64 + (((s * 4 + kg) ^ sw) * 8);
#pragma unroll
  for (int nt = 0; nt < 4; ++nt)
#pragma unroll
    for (int s = 0; s < 2; ++s)
      boff[nt][s] = (wn * 64 + nt * 16 + r15) * 64 + (((s * 4 + kg) ^ sw) * 8);

  f32x4 acc[2][4];
#pragma unroll
  for (int i = 0; i < 2; ++i)
#pragma unroll
    for (int j = 0; j < 4; ++j) acc[i][j] = (f32x4){0.f, 0.f, 0.f, 0.f};

  for (int k0 = 0; k0 < 512; k0 += 64) {
    glds16(gA0 + k0, lA0);
    glds16(gA1 + k0, lA1);
#pragma unroll
    for (int j = 0; j < 4; ++j) glds16(gB[j] + k0, lB[j]);
    __syncthreads();
#pragma unroll
    for (int s = 0; s < 2; ++s) {
      bf16x8 b[4];
#pragma unroll
      for (int nt = 0; nt < 4; ++nt) b[nt] = *(const bf16x8*)(sB + boff[nt][s]);
      bf16x8 a0 = *(const bf16x8*)(sA + aoff[0][s]);
      bf16x8 a1 = *(const bf16x8*)(sA + aoff[1][s]);
#pragma unroll
      for (int nt = 0; nt < 4; ++nt) {
        acc[0][nt] = mfma16(a0, b[nt], acc[0][nt]);
        acc[1][nt] = mfma16(a1, b[nt], acc[1][nt]);
      }
    }
    __syncthreads();
  }

  const int lq = l >> 4;
#pragma unroll
  for (int mt = 0; mt < 2; ++mt) {
    int row0 = mBase + wm * 32 + mt * 16 + lq * 4;
#pragma unroll
    for (int nt = 0; nt < 4; ++nt) {
      int col = nBase + wn * 64 + nt * 16 + r15;
      float bv = bias[col];
#pragma unroll
      for (int r = 0; r < 4; ++r)
        Cf[(size_t)(row0 + r) * 512 + col] = acc[mt][nt][r] + bv;
    }
  }
}

// ---------------------------------------------------------------------------
extern "C" void kernel_launch(void* const* d_in, const int* in_sizes, int n_in,
                              void* d_out, int out_size, void* d_ws, size_t ws_size,
                              hipStream_t stream) {
  const float* x     = (const float*)d_in[0];
  const float* w_qkv = (const float*)d_in[1];
  const float* b_qkv = (const float*)d_in[2];
  const float* w_out = (const float*)d_in[3];
  const float* b_out = (const float*)d_in[4];
  float* out = (float*)d_out;

  // workspace layout (~22.6 MB)
  char* ws = (char*)d_ws;
  u16* xh  = (u16*)(ws + 0);          // 4096x512 bf16 = 4194304
  u16* wqt = (u16*)(ws + 4194304);    // 1536x512 bf16 = 1572864
  u16* wot = (u16*)(ws + 5767168);    // 512x512 bf16  = 524288
  u16* qb  = (u16*)(ws + 6291456);    // 4096x512 bf16 (pre-scaled) = 4194304
  u16* kb  = (u16*)(ws + 10485760);   // 4194304
  u16* vb  = (u16*)(ws + 14680064);   // 4194304
  u16* aoh = (u16*)(ws + 18874368);   // 4194304

  prep<<<3072, 256, 0, stream>>>((const float4*)x, (uint2*)xh,
                                 w_qkv, wqt, w_out, wot);
  gemm_qkv<<<dim3(12, 64), 256, 0, stream>>>(xh, wqt, b_qkv, qb, kb, vb);
  attn_mfma<<<dim3(32, 8, 2), 256, 0, stream>>>(qb, kb, vb, aoh);
  gemm_out<<<dim3(4, 64), 256, 0, stream>>>(aoh, wot, b_out, out);
}